// Round 10
// baseline (370.735 us; speedup 1.0000x reference)
//
#include <hip/hip_runtime.h>
#include <cstdint>
#include <cstddef>

#define NI   256
#define QKC  32
#define BS   4
#define NPIX 4096   // 64*64

typedef __bf16 bf16x8 __attribute__((ext_vector_type(8)));
typedef __bf16 bf16x4 __attribute__((ext_vector_type(4)));
typedef float  f32x16 __attribute__((ext_vector_type(16)));

__device__ inline f32x16 zero16() {
    f32x16 z;
    #pragma unroll
    for (int i = 0; i < 16; ++i) z[i] = 0.f;
    return z;
}

// ---------------- Kernel 0: W fp32 -> bf16, concat [320][256] ----------------
__global__ __launch_bounds__(256) void wconv(
    const float* __restrict__ wq, const float* __restrict__ wk,
    const float* __restrict__ wv, __bf16* __restrict__ wbf)
{
    int f = (blockIdx.x * 256 + threadIdx.x) * 4;
    int row = f >> 8, c = f & 255;
    const float* src = row < 32 ? wq + row * NI + c
                     : row < 64 ? wk + (row - 32) * NI + c
                                : wv + (row - 64) * NI + c;
    float4 v = *(const float4*)src;
    __align__(8) __bf16 o4[4] = {(__bf16)v.x, (__bf16)v.y, (__bf16)v.z, (__bf16)v.w};
    *(uint2*)(wbf + f) = *(const uint2*)o4;
}

// ---------------- Kernel 1: QKV projection, single-stage, W direct from L2 ----------------
// q: (val)*log2e hi/lo split [b][n][32]; k: hi only [b][n][32]; v: bf16 [b][c][n].
__global__ __launch_bounds__(256) void qkv_mfma(
    const float* __restrict__ x, const __bf16* __restrict__ wbf,
    const float* __restrict__ bq, const float* __restrict__ bk,
    const float* __restrict__ bv,
    __bf16* __restrict__ qth, __bf16* __restrict__ qtl,
    __bf16* __restrict__ kth, __bf16* __restrict__ vb)
{
    __shared__ __align__(16) __bf16 xT[32][264];
    __shared__ float bls[320];

    const int t = threadIdx.x, w = t >> 6, lane = t & 63;
    const int l31 = lane & 31, h = lane >> 5;
    const int b = blockIdx.y, n0 = blockIdx.x * 32;

    for (int i = t; i < 320; i += 256)
        bls[i] = i < 32 ? bq[i] : i < 64 ? bk[i - 32] : bv[i - 64];

    {   // stage x transposed
        int n4 = (t & 7) * 4, cb = (t >> 3) * 8;
        float4 xv[8];
        #pragma unroll
        for (int j = 0; j < 8; ++j)
            xv[j] = *(const float4*)(x + ((size_t)(b * NI) + cb + j) * NPIX + n0 + n4);
        #pragma unroll
        for (int i = 0; i < 4; ++i) {
            __align__(16) __bf16 r8[8];
            #pragma unroll
            for (int j = 0; j < 8; ++j) r8[j] = (__bf16)((&xv[j].x)[i]);
            *(uint4*)&xT[n4 + i][cb] = *(const uint4*)r8;
        }
    }
    __syncthreads();

    f32x16 acc[3] = {zero16(), zero16(), zero16()};

    #pragma unroll 4
    for (int kk = 0; kk < 16; ++kk) {
        bf16x8 xf = *(const bf16x8*)&xT[l31][kk * 16 + 8 * h];
        #pragma unroll
        for (int jj = 0; jj < 3; ++jj) {
            int otl = w + 4 * jj;
            if (otl < 10) {
                bf16x8 wf = *(const bf16x8*)(wbf + (size_t)(otl * 32 + l31) * NI + kk * 16 + 8 * h);
                if (otl < 2)
                    acc[jj] = __builtin_amdgcn_mfma_f32_32x32x16_bf16(xf, wf, acc[jj], 0, 0, 0);
                else
                    acc[jj] = __builtin_amdgcn_mfma_f32_32x32x16_bf16(wf, xf, acc[jj], 0, 0, 0);
            }
        }
    }

    #pragma unroll
    for (int jj = 0; jj < 3; ++jj) {
        int otl = w + 4 * jj;
        if (otl >= 10) continue;
        const f32x16& A = acc[jj];
        if (otl < 2) {
            __bf16* dh = otl == 0 ? qth : kth;
            float bias = bls[otl * 32 + l31];
            float scale = otl == 0 ? 1.4426950408889634f : 1.0f;
            #pragma unroll
            for (int r = 0; r < 16; ++r) {
                int rit = (r & 3) + 8 * (r >> 2) + 4 * h;
                float val = (A[r] + bias) * scale;
                __bf16 hh = (__bf16)val;
                size_t idx = ((size_t)b * NPIX + n0 + rit) * QKC + l31;
                dh[idx] = hh;
                if (otl == 0) qtl[idx] = (__bf16)(val - (float)hh);
            }
        } else {
            #pragma unroll
            for (int r = 0; r < 16; ++r) {
                int rit = (r & 3) + 8 * (r >> 2) + 4 * h;
                int c = otl * 32 + rit - 64;
                float val = A[r] + bls[otl * 32 + rit];
                vb[((size_t)(b * NI) + c) * NPIX + n0 + l31] = (__bf16)val;
            }
        }
    }
}

// ---------------- Kernel 2: attention, BARRIER-FREE main loop ----------------
// grid (128 n-tiles of 32, 4 b) = 512 blocks of 256 thr, 2 blocks/CU.
// Wave w owns keys [32w,32w+32) of each 128-key m-tile, ALL 256 channels.
// S^T = MFMA(A=K, B=Q) -> P stays in registers as the PV B-operand; the
// fragment k-slot permutation pi(kc,h,j)=16kc+4h+(j&3)+8(j>>2) is applied to
// V's m-index at load time (sum over m is permutation-invariant).
// No LDS, no barriers in the loop. Epilogue: cross-wave O sum via LDS atomics.
__global__ __launch_bounds__(256, 2) void attn_mfma(
    const __bf16* __restrict__ qth, const __bf16* __restrict__ qtl,
    const __bf16* __restrict__ kth, const __bf16* __restrict__ vb,
    const float* __restrict__ x, const float* __restrict__ gamma,
    float* __restrict__ out)
{
    __shared__ float obuf[NI][36];   // 36864 B, c-major O^T accum
    __shared__ float dwave[4][32];
    __shared__ float rds[32];
    __shared__ float gls[NI];

    const int t    = threadIdx.x;
    const int b    = blockIdx.y;
    const int n0   = blockIdx.x * 32;
    const int w    = t >> 6;
    const int lane = t & 63;
    const int l31  = lane & 31;
    const int h    = lane >> 5;

    // zero obuf (9216 f32 = 2304 float4, 9 per thread), stage gamma
    {
        float* ofl = &obuf[0][0];
        #pragma unroll
        for (int i = 0; i < 9; ++i)
            *(float4*)&ofl[(t + 256 * i) * 4] = make_float4(0.f, 0.f, 0.f, 0.f);
        gls[t] = gamma[t];
    }
    __syncthreads();

    // Q B-fragments (col = n = l31), persistent
    const size_t qrow = ((size_t)b * NPIX + n0 + l31) * QKC;
    bf16x8 qh0 = *(const bf16x8*)(qth + qrow + 8 * h);
    bf16x8 qh1 = *(const bf16x8*)(qth + qrow + 16 + 8 * h);
    bf16x8 ql0 = *(const bf16x8*)(qtl + qrow + 8 * h);
    bf16x8 ql1 = *(const bf16x8*)(qtl + qrow + 16 + 8 * h);

    f32x16 acc[8] = {zero16(), zero16(), zero16(), zero16(),
                     zero16(), zero16(), zero16(), zero16()};
    float dacc = 0.f;

    const __bf16* kb = kth + ((size_t)b * NPIX + 32 * w + l31) * QKC + 8 * h;
    const __bf16* vbase = vb + ((size_t)(b * NI) + l31) * NPIX + 32 * w + 4 * h;

    for (int mt = 0; mt < NPIX / 128; ++mt) {
        // ---- S^T (32 keys x 32 n): A = K rows(keys), B = Q cols(n) ----
        const __bf16* kp = kb + (size_t)mt * 128 * QKC;
        bf16x8 k0 = *(const bf16x8*)kp;
        bf16x8 k1 = *(const bf16x8*)(kp + 16);
        f32x16 s = zero16();
        s = __builtin_amdgcn_mfma_f32_32x32x16_bf16(k0, qh0, s, 0, 0, 0);
        s = __builtin_amdgcn_mfma_f32_32x32x16_bf16(k1, qh1, s, 0, 0, 0);
        s = __builtin_amdgcn_mfma_f32_32x32x16_bf16(k0, ql0, s, 0, 0, 0);
        s = __builtin_amdgcn_mfma_f32_32x32x16_bf16(k1, ql1, s, 0, 0, 0);

        // ---- exp (q pre-scaled by log2e) -> bf16 B-fragments, d from SAME bf16 ----
        __bf16 pexp[16];
        #pragma unroll
        for (int r = 0; r < 16; ++r) {
            __bf16 pb = (__bf16)__builtin_amdgcn_exp2f(s[r]);
            pexp[r] = pb;
            dacc += (float)pb;
        }
        bf16x8 B0, B1;
        #pragma unroll
        for (int j = 0; j < 8; ++j) { B0[j] = pexp[j]; B1[j] = pexp[8 + j]; }

        // ---- PV: O^T[c][n] += V^T x P^T over this wave's 32 keys ----
        const __bf16* vp0 = vbase + (size_t)mt * 128;
        #pragma unroll
        for (int ct = 0; ct < 8; ++ct) {
            const __bf16* vp = vp0 + (size_t)(32 * ct) * NPIX;
            bf16x4 a0 = *(const bf16x4*)(vp);        // m: 4h+0..3
            bf16x4 a1 = *(const bf16x4*)(vp + 8);    // m: 8+4h+0..3
            bf16x4 a2 = *(const bf16x4*)(vp + 16);   // kc=1
            bf16x4 a3 = *(const bf16x4*)(vp + 24);
            bf16x8 A0 = {a0[0], a0[1], a0[2], a0[3], a1[0], a1[1], a1[2], a1[3]};
            bf16x8 A1 = {a2[0], a2[1], a2[2], a2[3], a3[0], a3[1], a3[2], a3[3]};
            acc[ct] = __builtin_amdgcn_mfma_f32_32x32x16_bf16(A0, B0, acc[ct], 0, 0, 0);
            acc[ct] = __builtin_amdgcn_mfma_f32_32x32x16_bf16(A1, B1, acc[ct], 0, 0, 0);
        }
    }

    // ---- epilogue ----
    float dtot = dacc + __shfl_xor(dacc, 32);
    if (lane < 32) dwave[w][lane] = dtot;

    #pragma unroll
    for (int ct = 0; ct < 8; ++ct)
        #pragma unroll
        for (int r = 0; r < 16; ++r) {
            int c = 32 * ct + (r & 3) + 8 * (r >> 2) + 4 * h;
            atomicAdd(&obuf[c][l31], acc[ct][r]);
        }
    __syncthreads();

    if (t < 32)
        rds[t] = 1.0f / (dwave[0][t] + dwave[1][t] + dwave[2][t] + dwave[3][t]);
    __syncthreads();

    const int n = t & 31, cb2 = (t >> 5) * 32;
    const float rd = rds[n];
    size_t gb = ((size_t)(b * NI + cb2)) * NPIX + n0 + n;
    #pragma unroll 4
    for (int i = 0; i < 32; ++i) {
        int c = cb2 + i;
        out[gb + (size_t)i * NPIX] =
            obuf[c][n] * rd * gls[c] + x[gb + (size_t)i * NPIX];
    }
}

extern "C" void kernel_launch(void* const* d_in, const int* in_sizes, int n_in,
                              void* d_out, int out_size, void* d_ws, size_t ws_size,
                              hipStream_t stream)
{
    const float* x     = (const float*)d_in[0];
    const float* wq    = (const float*)d_in[1];
    const float* bq    = (const float*)d_in[2];
    const float* wk    = (const float*)d_in[3];
    const float* bk    = (const float*)d_in[4];
    const float* wv    = (const float*)d_in[5];
    const float* bv    = (const float*)d_in[6];
    const float* gamma = (const float*)d_in[7];
    float* out = (float*)d_out;

    const size_t WSZ = (size_t)320 * NI;
    const size_t QSZ = (size_t)BS * NPIX * QKC;
    __bf16* wbf = (__bf16*)d_ws;
    __bf16* qth = wbf + WSZ;
    __bf16* qtl = qth + QSZ;
    __bf16* kth = qtl + QSZ;
    __bf16* vb  = kth + QSZ;

    wconv<<<dim3(80), 256, 0, stream>>>(wq, wk, wv, wbf);
    qkv_mfma<<<dim3(NPIX / 32, BS), 256, 0, stream>>>(x, wbf, bq, bk, bv,
                                                      qth, qtl, kth, vb);
    attn_mfma<<<dim3(NPIX / 32, BS), 256, 0, stream>>>(qth, qtl, kth, vb, x, gamma, out);
}

// Round 11
// 158.820 us; speedup vs baseline: 2.3343x; 2.3343x over previous
//
#include <hip/hip_runtime.h>
#include <cstdint>
#include <cstddef>

#define NI   256
#define QKC  32
#define BS   4
#define NPIX 4096   // 64*64
#define LOG2E 1.4426950408889634f

typedef __bf16 bf16x8 __attribute__((ext_vector_type(8)));
typedef __bf16 bf16x4 __attribute__((ext_vector_type(4)));
typedef float  f32x16 __attribute__((ext_vector_type(16)));

__device__ inline f32x16 zero16() {
    f32x16 z;
    #pragma unroll
    for (int i = 0; i < 16; ++i) z[i] = 0.f;
    return z;
}

// ---------------- Kernel 0: W -> fragment-packed bf16 ----------------
// wpack[otl(10)][kk(16)][h(2)][l31(32)][8]: A-frag-ready, 16B per (lane,kk).
__global__ __launch_bounds__(256) void wconv_pack(
    const float* __restrict__ wq, const float* __restrict__ wk,
    const float* __restrict__ wv, __bf16* __restrict__ wpk)
{
    int f = blockIdx.x * 256 + threadIdx.x;          // 0..10239
    int otl = f >> 10, rem = f & 1023;
    int kk = rem >> 6, h = (rem >> 5) & 1, l31 = rem & 31;
    int och = otl * 32 + l31, c0 = kk * 16 + 8 * h;
    const float* src = och < 32 ? wq + och * NI + c0
                     : och < 64 ? wk + (och - 32) * NI + c0
                                : wv + (och - 64) * NI + c0;
    float4 x0 = *(const float4*)src;
    float4 x1 = *(const float4*)(src + 4);
    __align__(16) __bf16 o8[8] = {
        (__bf16)x0.x, (__bf16)x0.y, (__bf16)x0.z, (__bf16)x0.w,
        (__bf16)x1.x, (__bf16)x1.y, (__bf16)x1.z, (__bf16)x1.w};
    *(uint4*)(wpk + (size_t)f * 8) = *(const uint4*)o8;
}

// ---------------- Kernel 1: QKV -> packed fragment outputs ----------------
// All tiles computed as C[och][n] (A=W, B=x). q/k packs come straight from
// C-regs (16B = regs 8kc..8kc+7, sigma-order consistent on both GEMM sides).
// v goes through one LDS transpose (reusing xT) into vpack.
__global__ __launch_bounds__(256) void qkv_mfma(
    const float* __restrict__ x, const __bf16* __restrict__ wpk,
    const float* __restrict__ bq, const float* __restrict__ bk,
    const float* __restrict__ bv,
    __bf16* __restrict__ qpk, __bf16* __restrict__ kpk, __bf16* __restrict__ vpk)
{
    __shared__ __align__(16) __bf16 xT[32][264];   // also reused as vT
    __shared__ float bls[320];

    const int t = threadIdx.x, w = t >> 6, lane = t & 63;
    const int l31 = lane & 31, h = lane >> 5;
    const int b = blockIdx.y, n0 = blockIdx.x * 32, kt = blockIdx.x;

    for (int i = t; i < 320; i += 256)
        bls[i] = i < 32 ? bq[i] : i < 64 ? bk[i - 32] : bv[i - 64];

    {   // stage x transposed (32 n x 256 c)
        int n4 = (t & 7) * 4, cb = (t >> 3) * 8;
        float4 xv[8];
        #pragma unroll
        for (int j = 0; j < 8; ++j)
            xv[j] = *(const float4*)(x + ((size_t)(b * NI) + cb + j) * NPIX + n0 + n4);
        #pragma unroll
        for (int i = 0; i < 4; ++i) {
            __align__(16) __bf16 r8[8];
            #pragma unroll
            for (int j = 0; j < 8; ++j) r8[j] = (__bf16)((&xv[j].x)[i]);
            *(uint4*)&xT[n4 + i][cb] = *(const uint4*)r8;
        }
    }
    __syncthreads();

    f32x16 acc[3] = {zero16(), zero16(), zero16()};
    #pragma unroll 4
    for (int kk = 0; kk < 16; ++kk) {
        bf16x8 xf = *(const bf16x8*)&xT[l31][kk * 16 + 8 * h];
        #pragma unroll
        for (int jj = 0; jj < 3; ++jj) {
            int otl = w + 4 * jj;
            if (otl < 10) {
                bf16x8 wf = *(const bf16x8*)(wpk + (size_t)((otl * 16 + kk) * 64 + 32 * h + l31) * 8);
                acc[jj] = __builtin_amdgcn_mfma_f32_32x32x16_bf16(wf, xf, acc[jj], 0, 0, 0);
            }
        }
    }
    __syncthreads();   // xT reads done; reuse as vT

    __bf16 (*vT)[264] = xT;
    // v tiles -> vT[key l31][c], b64 quad writes
    #pragma unroll
    for (int jj = 0; jj < 3; ++jj) {
        int otl = w + 4 * jj;
        if (otl >= 2 && otl < 10) {
            #pragma unroll
            for (int qd = 0; qd < 4; ++qd) {
                int c0v = (otl - 2) * 32 + 8 * qd + 4 * h;
                __align__(8) __bf16 q4[4];
                #pragma unroll
                for (int i = 0; i < 4; ++i)
                    q4[i] = (__bf16)(acc[jj][4 * qd + i] + bls[64 + c0v + i]);
                *(uint2*)&vT[l31][c0v] = *(const uint2*)q4;
            }
        }
    }
    // q/k packs straight from C-regs (coalesced b128 global stores)
    #pragma unroll
    for (int jj = 0; jj < 3; ++jj) {
        int otl = w + 4 * jj;
        if (otl == 0) {        // q: scale by log2e, hi/lo split
            #pragma unroll
            for (int kc = 0; kc < 2; ++kc) {
                __align__(16) __bf16 hi8[8], lo8[8];
                #pragma unroll
                for (int j = 0; j < 8; ++j) {
                    int r = 8 * kc + j;
                    int och = (r & 3) + 8 * (r >> 2) + 4 * h;
                    float val = (acc[jj][r] + bls[och]) * LOG2E;
                    __bf16 hh = (__bf16)val;
                    hi8[j] = hh;
                    lo8[j] = (__bf16)(val - (float)hh);
                }
                size_t base = ((((size_t)(b * 128 + kt) * 2 + 0) * 2 + kc) * 2 + h) * 32 + l31;
                *(uint4*)(qpk + base * 8) = *(const uint4*)hi8;
                size_t basel = ((((size_t)(b * 128 + kt) * 2 + 1) * 2 + kc) * 2 + h) * 32 + l31;
                *(uint4*)(qpk + basel * 8) = *(const uint4*)lo8;
            }
        } else if (otl == 1) { // k
            #pragma unroll
            for (int kc = 0; kc < 2; ++kc) {
                __align__(16) __bf16 k8[8];
                #pragma unroll
                for (int j = 0; j < 8; ++j) {
                    int r = 8 * kc + j;
                    int och = (r & 3) + 8 * (r >> 2) + 4 * h;
                    k8[j] = (__bf16)(acc[jj][r] + bls[32 + och]);
                }
                size_t base = (((size_t)(b * 128 + kt) * 2 + kc) * 2 + h) * 32 + l31;
                *(uint4*)(kpk + base * 8) = *(const uint4*)k8;
            }
        }
    }
    __syncthreads();   // vT complete

    // vpack emit: thread t owns c'=t; frag (kc,hh) = keys 16kc+8hh+j
    #pragma unroll
    for (int kc = 0; kc < 2; ++kc)
        #pragma unroll
        for (int hh = 0; hh < 2; ++hh) {
            __align__(16) __bf16 f8[8];
            #pragma unroll
            for (int j = 0; j < 8; ++j) f8[j] = vT[16 * kc + 8 * hh + j][t];
            size_t base = (((size_t)(b * 128 + kt) * 2 + kc) * 2 + hh) * 256 + t;
            *(uint4*)(vpk + base * 8) = *(const uint4*)f8;
        }
}

// ---------------- Kernel 2: attention, packed-coalesced loads ----------------
// grid (64 n-tiles, 2 k-halves, 4 b). Wave: sr=n-half, sc=key-half of S^T;
// PV: c-chunk 64w, all 64 n. pt_s[n][key] dbuf: 4 b64 writes, 8 b128 reads.
__global__ __launch_bounds__(256) void attn_mfma(
    const __bf16* __restrict__ qpk, const __bf16* __restrict__ kpk,
    const __bf16* __restrict__ vpk,
    __bf16* __restrict__ Opart, float* __restrict__ dpart)
{
    __shared__ __align__(16) __bf16 pt_s[2][64][72];   // 18432 B
    __shared__ float dwave[4][32];

    const int t = threadIdx.x;
    const int b = blockIdx.z, ksp = blockIdx.y;
    const int n0 = blockIdx.x * 64;
    const int w = t >> 6, lane = t & 63, l31 = lane & 31, h = lane >> 5;
    const int sr = w & 1, sc = w >> 1;
    const int kt0 = ksp * 64;

    // Q fragments (hi/lo x kc)
    const int qt = 2 * blockIdx.x + sr;
    bf16x8 qf[2][2];
    #pragma unroll
    for (int hl = 0; hl < 2; ++hl)
        #pragma unroll
        for (int kc = 0; kc < 2; ++kc)
            qf[hl][kc] = *(const bf16x8*)(qpk +
                (((((size_t)(b * 128 + qt) * 2 + hl) * 2 + kc) * 2 + h) * 32 + l31) * 8);

    auto kload = [&](int ktile, int kc) {
        return *(const bf16x8*)(kpk +
            ((((size_t)(b * 128 + ktile) * 2 + kc) * 2 + h) * 32 + l31) * 8);
    };

    f32x16 a00 = zero16(), a01 = zero16(), a10 = zero16(), a11 = zero16();
    float dacc = 0.f;

    auto sblock = [&](bf16x8 kh0, bf16x8 kh1, int buf) {
        f32x16 s = zero16();
        s = __builtin_amdgcn_mfma_f32_32x32x16_bf16(kh0, qf[0][0], s, 0, 0, 0);
        s = __builtin_amdgcn_mfma_f32_32x32x16_bf16(kh1, qf[0][1], s, 0, 0, 0);
        s = __builtin_amdgcn_mfma_f32_32x32x16_bf16(kh0, qf[1][0], s, 0, 0, 0);
        s = __builtin_amdgcn_mfma_f32_32x32x16_bf16(kh1, qf[1][1], s, 0, 0, 0);
        #pragma unroll
        for (int qd = 0; qd < 4; ++qd) {
            __align__(8) __bf16 e4[4];
            #pragma unroll
            for (int i = 0; i < 4; ++i) {
                float e = __builtin_amdgcn_exp2f(s[4 * qd + i]);
                dacc += e;
                e4[i] = (__bf16)e;
            }
            *(uint2*)&pt_s[buf][32 * sr + l31][32 * sc + 8 * qd + 4 * h] = *(const uint2*)e4;
        }
    };

    // prologue: S(0) -> pt[0], prefetch K(1)
    bf16x8 kh0 = kload(kt0 + sc, 0), kh1 = kload(kt0 + sc, 1);
    sblock(kh0, kh1, 0);
    kh0 = kload(kt0 + 2 + sc, 0); kh1 = kload(kt0 + 2 + sc, 1);
    __syncthreads();

    for (int mt = 0; mt < 32; ++mt) {
        const int cur = mt & 1;

        bf16x8 vf[2][2][2];
        #pragma unroll
        for (int i = 0; i < 2; ++i)
            #pragma unroll
            for (int kc = 0; kc < 2; ++kc)
                #pragma unroll
                for (int ctl = 0; ctl < 2; ++ctl)
                    vf[i][kc][ctl] = *(const bf16x8*)(vpk +
                        ((((size_t)(b * 128 + kt0 + 2 * mt + i) * 2 + kc) * 2 + h) * 256
                         + 64 * w + 32 * ctl + l31) * 8);

        if (mt < 31) {
            bf16x8 k0 = kh0, k1 = kh1;
            if (mt < 30) {
                kh0 = kload(kt0 + 2 * (mt + 2) + sc, 0);
                kh1 = kload(kt0 + 2 * (mt + 2) + sc, 1);
            }
            sblock(k0, k1, 1 - cur);
        }

        #pragma unroll
        for (int i = 0; i < 2; ++i)
            #pragma unroll
            for (int kc = 0; kc < 2; ++kc) {
                int col = 32 * i + 16 * kc + 8 * h;
                bf16x8 pa0 = *(const bf16x8*)&pt_s[cur][l31][col];
                bf16x8 pa1 = *(const bf16x8*)&pt_s[cur][32 + l31][col];
                a00 = __builtin_amdgcn_mfma_f32_32x32x16_bf16(pa0, vf[i][kc][0], a00, 0, 0, 0);
                a10 = __builtin_amdgcn_mfma_f32_32x32x16_bf16(pa1, vf[i][kc][0], a10, 0, 0, 0);
                a01 = __builtin_amdgcn_mfma_f32_32x32x16_bf16(pa0, vf[i][kc][1], a01, 0, 0, 0);
                a11 = __builtin_amdgcn_mfma_f32_32x32x16_bf16(pa1, vf[i][kc][1], a11, 0, 0, 0);
            }
        __syncthreads();
    }

    // ---- epilogue ----
    float dtot = dacc + __shfl_xor(dacc, 32);   // fold h halves (same n)
    if (lane < 32) dwave[w][l31] = dtot;
    __syncthreads();
    if (w < 2 && lane < 32) {
        size_t dbase = ((size_t)(ksp * BS + b)) * NPIX + n0 + 32 * w;
        dpart[dbase + l31] = dwave[w][l31] + dwave[w + 2][l31];
    }

    size_t obase = (((size_t)(ksp * BS + b)) * NI + 64 * w + l31) * NPIX + n0;
    #pragma unroll
    for (int rq = 0; rq < 4; ++rq) {
        int nn = 8 * rq + 4 * h;
        __align__(8) __bf16 t00[4], t10[4], t01[4], t11[4];
        #pragma unroll
        for (int i = 0; i < 4; ++i) {
            t00[i] = (__bf16)a00[4 * rq + i];
            t10[i] = (__bf16)a10[4 * rq + i];
            t01[i] = (__bf16)a01[4 * rq + i];
            t11[i] = (__bf16)a11[4 * rq + i];
        }
        *(uint2*)(Opart + obase + nn)                          = *(const uint2*)t00;
        *(uint2*)(Opart + obase + 32 + nn)                     = *(const uint2*)t10;
        *(uint2*)(Opart + obase + (size_t)32 * NPIX + nn)      = *(const uint2*)t01;
        *(uint2*)(Opart + obase + (size_t)32 * NPIX + 32 + nn) = *(const uint2*)t11;
    }
}

// ---------------- Kernel 3: combine ----------------
__global__ __launch_bounds__(256) void combine(
    const float* __restrict__ x, const float* __restrict__ gamma,
    const __bf16* __restrict__ Opart, const float* __restrict__ dpart,
    float* __restrict__ out)
{
    int idx = (blockIdx.x * 256 + threadIdx.x) * 4;
    int n = idx & (NPIX - 1);
    int c = (idx >> 12) & (NI - 1);
    int b = idx >> 20;

    size_t o0 = (((size_t)(0 * BS + b)) * NI + c) * NPIX + n;
    size_t o1 = (((size_t)(1 * BS + b)) * NI + c) * NPIX + n;
    bf16x4 p0 = *(const bf16x4*)(Opart + o0);
    bf16x4 p1 = *(const bf16x4*)(Opart + o1);
    float4 da = *(const float4*)(dpart + ((size_t)(0 * BS + b)) * NPIX + n);
    float4 db = *(const float4*)(dpart + ((size_t)(1 * BS + b)) * NPIX + n);
    size_t xb = ((size_t)(b * NI) + c) * NPIX + n;
    float4 xv = *(const float4*)(x + xb);
    float g = gamma[c];

    float4 r;
    r.x = g * (((float)p0[0] + (float)p1[0]) / (da.x + db.x)) + xv.x;
    r.y = g * (((float)p0[1] + (float)p1[1]) / (da.y + db.y)) + xv.y;
    r.z = g * (((float)p0[2] + (float)p1[2]) / (da.z + db.z)) + xv.z;
    r.w = g * (((float)p0[3] + (float)p1[3]) / (da.w + db.w)) + xv.w;
    *(float4*)(out + xb) = r;
}

extern "C" void kernel_launch(void* const* d_in, const int* in_sizes, int n_in,
                              void* d_out, int out_size, void* d_ws, size_t ws_size,
                              hipStream_t stream)
{
    const float* x     = (const float*)d_in[0];
    const float* wq    = (const float*)d_in[1];
    const float* bq    = (const float*)d_in[2];
    const float* wk    = (const float*)d_in[3];
    const float* bk    = (const float*)d_in[4];
    const float* wv    = (const float*)d_in[5];
    const float* bv    = (const float*)d_in[6];
    const float* gamma = (const float*)d_in[7];
    float* out = (float*)d_out;

    const size_t WPK = (size_t)10240 * 8;                 // 81920
    const size_t QPK = (size_t)BS * 128 * 2 * 2 * 2 * 32 * 8;  // 1,048,576
    const size_t KPK = (size_t)BS * 128 * 2 * 2 * 32 * 8;      // 524,288
    const size_t VPK = (size_t)BS * 128 * 2 * 2 * 256 * 8;     // 4,194,304
    const size_t OSZ = (size_t)2 * BS * NI * NPIX;             // 8,388,608
    __bf16* wpk   = (__bf16*)d_ws;
    __bf16* qpk   = wpk + WPK;
    __bf16* kpk   = qpk + QPK;
    __bf16* vpk   = kpk + KPK;
    __bf16* Opart = vpk + VPK;
    float*  dpart = (float*)(Opart + OSZ);

    wconv_pack<<<dim3(40), 256, 0, stream>>>(wq, wk, wv, wpk);
    qkv_mfma<<<dim3(NPIX / 32, BS), 256, 0, stream>>>(x, wpk, bq, bk, bv, qpk, kpk, vpk);
    attn_mfma<<<dim3(64, 2, BS), 256, 0, stream>>>(qpk, kpk, vpk, Opart, dpart);
    combine<<<dim3(BS * NI * NPIX / 1024), 256, 0, stream>>>(x, gamma, Opart, dpart, out);
}